// Round 17
// baseline (84.474 us; speedup 1.0000x reference)
//
#include <hip/hip_runtime.h>
#include <math.h>

#define Bb 2
#define Lq 512
#define CS 384
#define CZ 128
#define Hh 8
#define HD 16
#define NEG_MAX -3.4028234663852886e38f

typedef float f2_t __attribute__((ext_vector_type(2)));
typedef float f4_t __attribute__((ext_vector_type(4)));

__device__ inline float wave_reduce_sum(float v) {
    #pragma unroll
    for (int off = 32; off > 0; off >>= 1) v += __shfl_xor(v, off, 64);
    return v;
}
__device__ inline void wave_reduce_sum2(float& a, float& b) {
    #pragma unroll
    for (int off = 32; off > 0; off >>= 1) {
        a += __shfl_xor(a, off, 64);
        b += __shfl_xor(b, off, 64);
    }
}
__device__ inline void wave_reduce_max2(float& a, float& b) {
    #pragma unroll
    for (int off = 32; off > 0; off >>= 1) {
        a = fmaxf(a, __shfl_xor(a, off, 64));
        b = fmaxf(b, __shfl_xor(b, off, 64));
    }
}

// Fused: x = rmsnorm(s @ W_s^T, g_s) in LDS, qk = x @ W_qk^T + RoPE. (round-7/12 proven)
__global__ __launch_bounds__(256) void k_proj(const float* __restrict__ s,
        const float* __restrict__ W_s, const float* __restrict__ g_s,
        const float* __restrict__ W_qk, float* __restrict__ qk_ws) {
    int blk = blockIdx.x;            // rows blk*4 .. blk*4+3
    int t = threadIdx.x;             // 0..255
    __shared__ float s_lds[4*CS];
    __shared__ float x_lds[4*CZ];
    __shared__ float qkrow[4][2*CZ];
    __shared__ float red[4][2];
    size_t base = (size_t)blk * 4 * CS;
    for (int i = t; i < 4*CS; i += 256) s_lds[i] = s[base + i];
    __syncthreads();

    int c = t & 127, rpair = t >> 7;
    float aA = 0.f, aB = 0.f;
    {
        const float4* w4 = (const float4*)(W_s + (size_t)c * CS);
        const float4* sA = (const float4*)(s_lds + (2*rpair    )*CS);
        const float4* sB = (const float4*)(s_lds + (2*rpair + 1)*CS);
        #pragma unroll 4
        for (int i = 0; i < CS/4; ++i) {
            float4 w = w4[i];
            float4 vA = sA[i], vB = sB[i];
            aA += w.x*vA.x + w.y*vA.y + w.z*vA.z + w.w*vA.w;
            aB += w.x*vB.x + w.y*vB.y + w.z*vB.z + w.w*vB.w;
        }
    }
    {
        float sA = aA*aA, sB = aB*aB;
        wave_reduce_sum2(sA, sB);
        int lane = t & 63, wid = t >> 6;
        if (lane == 0) { red[wid][0] = sA; red[wid][1] = sB; }
    }
    __syncthreads();
    {
        float g = g_s[c];
        int w0 = (rpair == 0) ? 0 : 2;
        float tA = red[w0][0] + red[w0+1][0];
        float tB = red[w0][1] + red[w0+1][1];
        x_lds[(2*rpair  )*CZ + c] = aA * rsqrtf(tA*(1.f/CZ) + 1e-5f) * g;
        x_lds[(2*rpair+1)*CZ + c] = aB * rsqrtf(tB*(1.f/CZ) + 1e-5f) * g;
    }
    __syncthreads();

    {
        const float4* w4 = (const float4*)(W_qk + (size_t)t * CZ);
        const float4* x0 = (const float4*)(x_lds);
        const float4* x1 = (const float4*)(x_lds + CZ);
        const float4* x2 = (const float4*)(x_lds + 2*CZ);
        const float4* x3 = (const float4*)(x_lds + 3*CZ);
        float q0=0.f, q1=0.f, q2=0.f, q3=0.f;
        #pragma unroll 4
        for (int i = 0; i < CZ/4; ++i) {
            float4 w = w4[i];
            float4 v0=x0[i], v1=x1[i], v2=x2[i], v3=x3[i];
            q0 += w.x*v0.x + w.y*v0.y + w.z*v0.z + w.w*v0.w;
            q1 += w.x*v1.x + w.y*v1.y + w.z*v1.z + w.w*v1.w;
            q2 += w.x*v2.x + w.y*v2.y + w.z*v2.z + w.w*v2.w;
            q3 += w.x*v3.x + w.y*v3.y + w.z*v3.z + w.w*v3.w;
        }
        qkrow[0][t]=q0; qkrow[1][t]=q1; qkrow[2][t]=q2; qkrow[3][t]=q3;
    }
    __syncthreads();
    {
        int half = t >> 7, within = t & 127, h = within >> 4, dd = within & 15, d = dd >> 1;
        int row0 = blk * 4;
        int b = row0 >> 9;
        float inv = exp2f(-(float)(2*d) * (1.f/16.f) * 13.287712379549449f); // 10000^(-2d/16)
        #pragma unroll
        for (int r = 0; r < 4; ++r) {
            int l = (row0 + r) & (Lq - 1);
            float ang = (float)l * inv;
            float cv = cosf(ang), sn = sinf(ang);
            float xr = qkrow[r][t & ~1];
            float xi = qkrow[r][t | 1];
            float outv = (dd & 1) ? (xr*sn + xi*cv) : (xr*cv - xi*sn);
            size_t idx = ((((size_t)half*Bb + b)*Hh + h)*Lq + l)*HD + dd;
            qk_ws[idx] = outv;
        }
    }
}

// k_attn2: 2 query rows (l0, l0+1) per block. K rows loaded ONCE, dotted with both q's
// (halves L2 K-read traffic; amortizes prologue over 2x stores). Gram rmsnorm; phase 2
// = proven half-wave/4ch/f4-nt shape over 1024 combined rows.
__global__ __launch_bounds__(512) void k_attn2(const float* __restrict__ qk_ws,
        const int* __restrict__ mask, const float* __restrict__ W_o,
        const float* __restrict__ g_z, float* __restrict__ out) {
    int bid = blockIdx.x;            // b*256 + lp
    int lp = bid & 255;
    int b = bid >> 8;
    int l0 = lp * 2;
    int t = threadIdx.x;
    int w = t >> 6, lane = t & 63;
    __shared__ float p_lds[2][Hh][Lq];   // 32 KB
    __shared__ float sc_lds[2][Lq];      // 4 KB
    __shared__ float q_lds[2][CZ];       // 1 KB
    __shared__ float g_lds[Hh*Hh];
    if (t < 2*CZ) {
        int rl = t >> 7, within = t & 127;
        int qh = within >> 4, dd = within & 15;
        q_lds[rl][within] = qk_ws[(((size_t)b*Hh + qh)*Lq + (l0 + rl))*HD + dd];
    }
    // Gram: wave w computes G[w][k]
    {
        int k = lane & 7, cg = lane >> 3;
        float partial = 0.f;
        #pragma unroll
        for (int cc = 0; cc < 16; ++cc) {
            int cidx = cg*16 + cc;
            partial += W_o[cidx*Hh + w] * W_o[cidx*Hh + k];
        }
        partial += __shfl_xor(partial, 8, 64);
        partial += __shfl_xor(partial, 16, 64);
        partial += __shfl_xor(partial, 32, 64);
        if (lane < 8) g_lds[w*Hh + lane] = partial;
    }
    int maskL0 = mask[b*Lq + l0];
    int maskL1 = mask[b*Lq + l0 + 1];
    __syncthreads();

    // ---- phase 1: wave w == head h; both l's share each K row ----
    {
        int h = w;
        const float* kbase = qk_ws + ((((size_t)Bb + b)*Hh + h)*Lq)*HD;
        float q0[HD], q1[HD];
        #pragma unroll
        for (int d = 0; d < HD; ++d) { q0[d] = q_lds[0][h*HD + d]; q1[d] = q_lds[1][h*HD + d]; }
        float sv0[8], sv1[8];
        float mx0 = NEG_MAX, mx1 = NEG_MAX;
        #pragma unroll 4
        for (int i = 0; i < 8; ++i) {
            int m = i*64 + lane;
            const float4* k4 = (const float4*)(kbase + (size_t)m * HD);
            float4 k0=k4[0], k1=k4[1], k2=k4[2], k3=k4[3];
            float a0 = q0[0]*k0.x + q0[1]*k0.y + q0[2]*k0.z + q0[3]*k0.w
                     + q0[4]*k1.x + q0[5]*k1.y + q0[6]*k1.z + q0[7]*k1.w
                     + q0[8]*k2.x + q0[9]*k2.y + q0[10]*k2.z + q0[11]*k2.w
                     + q0[12]*k3.x + q0[13]*k3.y + q0[14]*k3.z + q0[15]*k3.w;
            float a1 = q1[0]*k0.x + q1[1]*k0.y + q1[2]*k0.z + q1[3]*k0.w
                     + q1[4]*k1.x + q1[5]*k1.y + q1[6]*k1.z + q1[7]*k1.w
                     + q1[8]*k2.x + q1[9]*k2.y + q1[10]*k2.z + q1[11]*k2.w
                     + q1[12]*k3.x + q1[13]*k3.y + q1[14]*k3.z + q1[15]*k3.w;
            int pm = mask[b*Lq + m];
            sv0[i] = (maskL0 & pm) ? a0*0.25f : NEG_MAX;
            sv1[i] = (maskL1 & pm) ? a1*0.25f : NEG_MAX;
            mx0 = fmaxf(mx0, sv0[i]);
            mx1 = fmaxf(mx1, sv1[i]);
        }
        wave_reduce_max2(mx0, mx1);
        float e0[8], e1[8];
        float sum0 = 0.f, sum1 = 0.f;
        #pragma unroll
        for (int i = 0; i < 8; ++i) {
            e0[i] = __expf(sv0[i]-mx0); sum0 += e0[i];
            e1[i] = __expf(sv1[i]-mx1); sum1 += e1[i];
        }
        wave_reduce_sum2(sum0, sum1);
        float inv0 = 1.f / sum0, inv1 = 1.f / sum1;
        #pragma unroll
        for (int i = 0; i < 8; ++i) {
            p_lds[0][h][i*64+lane] = e0[i]*inv0;
            p_lds[1][h][i*64+lane] = e1[i]*inv1;
        }
    }
    __syncthreads();

    // ---- phase 1.5: sc[rl][m] = rsqrt(p^T G p / 128 + eps), thread t = row t ----
    #pragma unroll
    for (int rl = 0; rl < 2; ++rl) {
        float p[8];
        #pragma unroll
        for (int k = 0; k < 8; ++k) p[k] = p_lds[rl][k][t];
        float ss = 0.f;
        #pragma unroll
        for (int j = 0; j < 8; ++j) {
            float4 gA = *(const float4*)&g_lds[j*8];
            float4 gB = *(const float4*)&g_lds[j*8 + 4];
            float qj = gA.x*p[0] + gA.y*p[1] + gA.z*p[2] + gA.w*p[3]
                     + gB.x*p[4] + gB.y*p[5] + gB.z*p[6] + gB.w*p[7];
            ss += p[j]*qj;
        }
        sc_lds[rl][t] = rsqrtf(ss*(1.f/CZ) + 1e-5f);
    }

    // per-lane output weights: 4 ch/lane (half-wave covers the 128 channels)
    int g2 = lane >> 5, cl = lane & 31, c0 = cl * 4;
    f4_t wv4[Hh];
    {
        const float4* wp = (const float4*)(W_o + (size_t)c0 * Hh);
        float4 R0a=wp[0], R0b=wp[1], R1a=wp[2], R1b=wp[3];
        float4 R2a=wp[4], R2b=wp[5], R3a=wp[6], R3b=wp[7];
        wv4[0] = f4_t{R0a.x, R1a.x, R2a.x, R3a.x};
        wv4[1] = f4_t{R0a.y, R1a.y, R2a.y, R3a.y};
        wv4[2] = f4_t{R0a.z, R1a.z, R2a.z, R3a.z};
        wv4[3] = f4_t{R0a.w, R1a.w, R2a.w, R3a.w};
        wv4[4] = f4_t{R0b.x, R1b.x, R2b.x, R3b.x};
        wv4[5] = f4_t{R0b.y, R1b.y, R2b.y, R3b.y};
        wv4[6] = f4_t{R0b.z, R1b.z, R2b.z, R3b.z};
        wv4[7] = f4_t{R0b.w, R1b.w, R2b.w, R3b.w};
    }
    f4_t gz4 = *(const f4_t*)(g_z + c0);
    __syncthreads();

    // ---- phase 2: 1024 combined rows. waves 0-3 -> l0, waves 4-7 -> l0+1;
    //      each wave owns a 128-row strip; half-wave per row; f4 nt stores ----
    int lsel = w >> 2, mb = (w & 3) * 128;
    float* obase = out + ((size_t)(b*Lq + l0 + lsel) * Lq) * CZ;
    const float* psel = &p_lds[lsel][0][0];
    const float* scsel = &sc_lds[lsel][0];
    #pragma unroll 1
    for (int i = 0; i < 64; ++i) {
        int m = mb + i*2 + g2;
        float pp[Hh];
        #pragma unroll
        for (int k = 0; k < Hh; ++k) pp[k] = psel[k*Lq + m];
        float sc = scsel[m];
        f4_t a = {0.f, 0.f, 0.f, 0.f};
        #pragma unroll
        for (int k = 0; k < Hh; ++k) a += pp[k] * wv4[k];
        a *= sc * gz4;
        __builtin_nontemporal_store(a, (f4_t*)(obase + (size_t)m*CZ + c0));
    }
}

extern "C" void kernel_launch(void* const* d_in, const int* in_sizes, int n_in,
                              void* d_out, int out_size, void* d_ws, size_t ws_size,
                              hipStream_t stream) {
    const float* s    = (const float*)d_in[0];
    const int*   mask = (const int*)d_in[1];
    const float* W_s  = (const float*)d_in[2];
    const float* g_s  = (const float*)d_in[3];
    const float* W_qk = (const float*)d_in[4];
    const float* W_o  = (const float*)d_in[5];
    const float* g_z  = (const float*)d_in[6];
    float* out = (float*)d_out;
    float* ws  = (float*)d_ws;

    float* qk_ws = ws;               // 2*2*8*512*16 floats = 1 MB

    k_proj<<<256, 256, 0, stream>>>(s, W_s, g_s, W_qk, qk_ws);
    k_attn2<<<Bb*Lq/2, 512, 0, stream>>>(qk_ws, mask, W_o, g_z, out);
}